// Round 9
// baseline (57.569 us; speedup 1.0000x reference)
//
#include <hip/hip_runtime.h>
#include <math.h>

#define EPSF 1.1920929e-07f
#define PLANES 4           // planes per block; grid = 8192/PLANES = 2048 = 8 blocks/CU

typedef float f4 __attribute__((ext_vector_type(4)));

__device__ __forceinline__ float sigmoidf_(float v) { return 1.0f / (1.0f + expf(-v)); }

// ---------------------------------------------------------------------------
// Fused, PLANES consecutive (b,c,x) planes per block (2048 blocks, 256 thr,
// full 32 waves/CU). R3-proven LDS preamble once per block; streaming loop is
// unroll-2 software-pipelined NT load -> fma -> NT store.
// ---------------------------------------------------------------------------
__global__ void __launch_bounds__(256) fused_kernel(
        const float* __restrict__ xin, const float* __restrict__ tab,
        const float* __restrict__ w1,  const float* __restrict__ b1,
        const float* __restrict__ w2,  const float* __restrict__ b2,
        const float* __restrict__ wp,  const float* __restrict__ bp,
        const float* __restrict__ wsg, const float* __restrict__ bsg,
        float* __restrict__ out, int out_last)
{
    __shared__ float emb1[2][32];
    __shared__ float emb2[2][32];
    __shared__ float head[8];
    __shared__ float gys[64];
    __shared__ f4    gz4[16];
    __shared__ float pvs[PLANES];
    __shared__ float sh_sh;

    const int g   = blockIdx.x;          // plane-group: 16 groups per (b,c)
    const int bc  = g >> 4;
    const int xi0 = (g & 15) * PLANES;
    const int b   = bc >> 6;
    const int c   = bc & 63;
    const int tid = threadIdx.x;

    // MLP layer 1 (both batches on 64 threads)
    if (tid < 64) {
        int bb = tid >> 5, j = tid & 31;
        float acc = b1[j];
        #pragma unroll
        for (int k = 0; k < 6; ++k) acc += tab[bb * 6 + k] * w1[j * 6 + k];
        emb1[bb][j] = tanhf(acc);
    }
    __syncthreads();

    // MLP layer 2
    if (tid < 64) {
        int bb = tid >> 5, j = tid & 31;
        float acc = b2[j];
        #pragma unroll
        for (int k = 0; k < 32; ++k) acc += emb1[bb][k] * w2[j * 32 + k];
        emb2[bb][j] = tanhf(acc);
    }
    __syncthreads();

    // 8 head values: 0:scale 1:shift 2:mu_a 3:mu_b 4:mu_c 5:sa 6:sb 7:sc
    if (tid < 8) {
        const float* W  = (tid < 5) ? wp  : wsg;
        const float* Bv = (tid < 5) ? bp  : bsg;
        int row = ((tid < 5) ? tid : (tid - 5)) * 64 + c;
        float acc = Bv[row];
        #pragma unroll
        for (int k = 0; k < 32; ++k) acc += emb2[b][k] * W[row * 32 + k];
        head[tid] = acc;
    }
    __syncthreads();

    // gaussian tables + per-plane constants
    if (tid < 64) {
        float m  = tanhf(head[3]) * 32.0f + 31.5f;
        float sg = sigmoidf_(head[6]) * 3.5f + EPSF;
        float d  = ((float)tid - m) / sg;
        gys[tid] = expf(-0.5f * d * d);
    } else if (tid < 128) {
        int i = tid - 64;
        float m  = tanhf(head[4]) * 32.0f + 31.5f;
        float sg = sigmoidf_(head[7]) * 3.5f + EPSF;
        float d  = ((float)i - m) / sg;
        ((float*)gz4)[i] = expf(-0.5f * d * d);
    } else if (tid < 128 + PLANES) {
        int p = tid - 128;
        float m  = tanhf(head[2]) * 32.0f + 31.5f;
        float sg = sigmoidf_(head[5]) * 3.5f + EPSF;
        float d  = ((float)(xi0 + p) - m) / sg;
        pvs[p] = (1.0f - head[0]) * expf(-0.5f * d * d);
        if (p == 0) sh_sh = head[1];
    }

    // block 0 only: l2 scalar
    if (g == 0) {
        __shared__ float sq[5][128];
        for (int t = tid; t < 640; t += 256) {
            int q = t / 128, r = t % 128;
            int bb = r >> 6, cc = r & 63;
            const float* W  = (q < 2) ? wp  : wsg;
            const float* Bv = (q < 2) ? bp  : bsg;
            int row = ((q < 2) ? q : (q - 2)) * 64 + cc;
            float acc = Bv[row];
            #pragma unroll
            for (int k = 0; k < 32; ++k) acc += emb2[bb][k] * W[row * 32 + k];
            if (q >= 2) acc = sigmoidf_(acc);
            sq[q][r] = acc * acc;
        }
        __syncthreads();
        if (tid == 0) {
            float tot = 0.0f;
            for (int q = 0; q < 5; ++q) {
                float ssum = 0.0f;
                for (int i = 0; i < 128; ++i) ssum += sq[q][i];
                tot += sqrtf(ssum);
            }
            out[out_last] = tot;
        }
    }
    __syncthreads();

    // ---- streaming: unroll-2 pipelined over PLANES planes ----
    const float sh = sh_sh;
    const int   yb = tid >> 4;
    const f4    vz = gz4[tid & 15];
    const float gy0 = gys[yb], gy1 = gys[yb + 16],
                gy2 = gys[yb + 32], gy3 = gys[yb + 48];
    const f4 shv = {sh, sh, sh, sh};

    const f4* x4 = (const f4*)(xin + (size_t)g * (PLANES * 4096));
    f4*       o4 = (f4*)(out + (size_t)g * (PLANES * 4096));

    #pragma unroll 2
    for (int p = 0; p < PLANES; ++p) {
        const float pv = pvs[p];
        const int base = p * 1024 + tid;
        f4 a0 = __builtin_nontemporal_load(&x4[base]);
        f4 a1 = __builtin_nontemporal_load(&x4[base + 256]);
        f4 a2 = __builtin_nontemporal_load(&x4[base + 512]);
        f4 a3 = __builtin_nontemporal_load(&x4[base + 768]);
        __builtin_nontemporal_store((vz * a0) * (pv * gy0) + shv, &o4[base]);
        __builtin_nontemporal_store((vz * a1) * (pv * gy1) + shv, &o4[base + 256]);
        __builtin_nontemporal_store((vz * a2) * (pv * gy2) + shv, &o4[base + 512]);
        __builtin_nontemporal_store((vz * a3) * (pv * gy3) + shv, &o4[base + 768]);
    }
}

// ---------------------------------------------------------------------------
extern "C" void kernel_launch(void* const* d_in, const int* in_sizes, int n_in,
                              void* d_out, int out_size, void* d_ws, size_t ws_size,
                              hipStream_t stream)
{
    const float* x   = (const float*)d_in[0];
    const float* tab = (const float*)d_in[1];
    const float* w1  = (const float*)d_in[2];
    const float* b1  = (const float*)d_in[3];
    const float* w2  = (const float*)d_in[4];
    const float* b2  = (const float*)d_in[5];
    const float* wp  = (const float*)d_in[6];
    const float* bp  = (const float*)d_in[7];
    const float* wsg = (const float*)d_in[8];
    const float* bsg = (const float*)d_in[9];

    float* out = (float*)d_out;

    fused_kernel<<<(2 * 64 * 64) / PLANES, 256, 0, stream>>>(
        x, tab, w1, b1, w2, b2, wp, bp, wsg, bsg, out, out_size - 1);
}

// Round 10
// 49.897 us; speedup vs baseline: 1.1538x; 1.1538x over previous
//
#include <hip/hip_runtime.h>
#include <math.h>

#define EPSF 1.1920929e-07f

typedef float f4 __attribute__((ext_vector_type(4)));

__device__ __forceinline__ float sigmoidf_(float v) { return 1.0f / (1.0f + expf(-v)); }

// ---------------------------------------------------------------------------
// Fully fused, one (b,c,x) plane of 64x64 per block (8192 blocks, 256 thr).
// Proven-best form (R3, 49.5 us): LDS preamble once per block, streaming body
// of 4 NT loads -> packed fma -> 4 NT stores. Block 0 also computes l2.
// ---------------------------------------------------------------------------
__global__ void __launch_bounds__(256) fused_kernel(
        const float* __restrict__ xin, const float* __restrict__ tab,
        const float* __restrict__ w1,  const float* __restrict__ b1,
        const float* __restrict__ w2,  const float* __restrict__ b2,
        const float* __restrict__ wp,  const float* __restrict__ bp,
        const float* __restrict__ wsg, const float* __restrict__ bsg,
        float* __restrict__ out, int out_last)
{
    __shared__ float emb1[2][32];
    __shared__ float emb2[2][32];
    __shared__ float head[8];
    __shared__ float gys[64];
    __shared__ f4    gz4[16];
    __shared__ float pv_sh, sh_sh;

    const int blk = blockIdx.x;        // b*64*64 + c*64 + x
    const int bc  = blk >> 6;
    const int xi  = blk & 63;
    const int b   = bc >> 6;
    const int c   = bc & 63;
    const int tid = threadIdx.x;

    // MLP layer 1: emb1[bb][j] = tanh(tab[bb] @ w1.T + b1), both batches
    if (tid < 64) {
        int bb = tid >> 5, j = tid & 31;
        float acc = b1[j];
        #pragma unroll
        for (int k = 0; k < 6; ++k) acc += tab[bb * 6 + k] * w1[j * 6 + k];
        emb1[bb][j] = tanhf(acc);
    }
    __syncthreads();

    // MLP layer 2
    if (tid < 64) {
        int bb = tid >> 5, j = tid & 31;
        float acc = b2[j];
        #pragma unroll
        for (int k = 0; k < 32; ++k) acc += emb1[bb][k] * w2[j * 32 + k];
        emb2[bb][j] = tanhf(acc);
    }
    __syncthreads();

    // 8 head values for this (b,c):
    // 0:scale 1:shift 2:mu_a 3:mu_b 4:mu_c   (wp rows q*64+c)
    // 5:sa 6:sb 7:sc                          (ws rows (q-5)*64+c)
    if (tid < 8) {
        const float* W  = (tid < 5) ? wp  : wsg;
        const float* Bv = (tid < 5) ? bp  : bsg;
        int row = ((tid < 5) ? tid : (tid - 5)) * 64 + c;
        float acc = Bv[row];
        #pragma unroll
        for (int k = 0; k < 32; ++k) acc += emb2[b][k] * W[row * 32 + k];
        head[tid] = acc;
    }
    __syncthreads();

    // gaussian tables + plane constants
    if (tid < 64) {
        float m  = tanhf(head[3]) * 32.0f + 31.5f;
        float sg = sigmoidf_(head[6]) * 3.5f + EPSF;
        float d  = ((float)tid - m) / sg;
        gys[tid] = expf(-0.5f * d * d);
    } else if (tid < 128) {
        int i = tid - 64;
        float m  = tanhf(head[4]) * 32.0f + 31.5f;
        float sg = sigmoidf_(head[7]) * 3.5f + EPSF;
        float d  = ((float)i - m) / sg;
        ((float*)gz4)[i] = expf(-0.5f * d * d);
    } else if (tid == 128) {
        float m  = tanhf(head[2]) * 32.0f + 31.5f;
        float sg = sigmoidf_(head[5]) * 3.5f + EPSF;
        float d  = ((float)xi - m) / sg;
        pv_sh = (1.0f - head[0]) * expf(-0.5f * d * d);
        sh_sh = head[1];
    }

    // block 0 only: l2 = sum of 5 frobenius norms
    if (blk == 0) {
        __shared__ float sq[5][128];
        for (int t = tid; t < 640; t += 256) {
            int q = t / 128, r = t % 128;
            int bb = r >> 6, cc = r & 63;
            const float* W  = (q < 2) ? wp  : wsg;
            const float* Bv = (q < 2) ? bp  : bsg;
            int row = ((q < 2) ? q : (q - 2)) * 64 + cc;
            float acc = Bv[row];
            #pragma unroll
            for (int k = 0; k < 32; ++k) acc += emb2[bb][k] * W[row * 32 + k];
            if (q >= 2) acc = sigmoidf_(acc);
            sq[q][r] = acc * acc;
        }
        __syncthreads();
        if (tid == 0) {
            float tot = 0.0f;
            for (int q = 0; q < 5; ++q) {
                float ssum = 0.0f;
                for (int i = 0; i < 128; ++i) ssum += sq[q][i];
                tot += sqrtf(ssum);
            }
            out[out_last] = tot;
        }
    }
    __syncthreads();

    // streaming phase: out = pv*gy[y]*gz[z] * x + sh over this 64x64 plane
    const float pv = pv_sh;
    const float sh = sh_sh;
    const f4* x4 = (const f4*)(xin + (size_t)blk * 4096);
    f4*       o4 = (f4*)(out + (size_t)blk * 4096);

    #pragma unroll
    for (int k = 0; k < 4; ++k) {
        int i4 = tid + k * 256;        // 1024 float4s per plane
        int y  = i4 >> 4;
        int z0 = (i4 & 15) << 2;
        f4 xv = __builtin_nontemporal_load(&x4[i4]);
        float m = pv * gys[y];
        f4 ov;
        ov.x = fmaf(m * gz4[0][0], 0.0f, 0.0f);   // placeholder removed below
        (void)ov;
        f4 gz = gz4[i4 & 15];
        f4 o;
        o.x = fmaf(m * gz.x, xv.x, sh);
        o.y = fmaf(m * gz.y, xv.y, sh);
        o.z = fmaf(m * gz.z, xv.z, sh);
        o.w = fmaf(m * gz.w, xv.w, sh);
        __builtin_nontemporal_store(o, &o4[i4]);
        (void)z0;
    }
}

// ---------------------------------------------------------------------------
extern "C" void kernel_launch(void* const* d_in, const int* in_sizes, int n_in,
                              void* d_out, int out_size, void* d_ws, size_t ws_size,
                              hipStream_t stream)
{
    const float* x   = (const float*)d_in[0];
    const float* tab = (const float*)d_in[1];
    const float* w1  = (const float*)d_in[2];
    const float* b1  = (const float*)d_in[3];
    const float* w2  = (const float*)d_in[4];
    const float* b2  = (const float*)d_in[5];
    const float* wp  = (const float*)d_in[6];
    const float* bp  = (const float*)d_in[7];
    const float* wsg = (const float*)d_in[8];
    const float* bsg = (const float*)d_in[9];

    float* out = (float*)d_out;

    fused_kernel<<<2 * 64 * 64, 256, 0, stream>>>(
        x, tab, w1, b1, w2, b2, wp, bp, wsg, bsg, out, out_size - 1);
}